// Round 1
// baseline (88.613 us; speedup 1.0000x reference)
//
#include <hip/hip_runtime.h>

#define N 512
#define D 384
#define NF4 (D / 4)   // 96 float4 per embedding row

#if __has_builtin(__builtin_amdgcn_exp2f)
#define EXP2F(x) __builtin_amdgcn_exp2f(x)
#else
#define EXP2F(x) exp2f(x)
#endif
#if __has_builtin(__builtin_amdgcn_rcpf)
#define RCPF(x) __builtin_amdgcn_rcpf(x)
#else
#define RCPF(x) (1.0f / (x))
#endif

// Fused dist+loss: one block handles queries q0=b and q1=b+256.
// Phase 1: thread t computes d(q0, j=t) and d(q1, j=t) by streaming row t of
// emb once (per-lane row pattern; lines are L1/L2-resident, emb fits in each
// XCD's 4 MiB L2, so per-block 786 KB re-read is L2-served). Distance rows
// live in LDS, pre-scaled by C = (1/T2)*log2(e); the 1 MiB dist global
// round-trip and two launch gaps of the 3-kernel chain are eliminated.
// Phase 2: identical softrank math to the verified kernel -- waves 0-3 own
// q0's GT columns, waves 4-7 own q1's; lanes parallel over the 512-term
// m-sum (stride-1 LDS, conflict-free).
__global__ __launch_bounds__(512) void fused_kernel(const float* __restrict__ emb,
                                                    const int* __restrict__ labels,
                                                    float* __restrict__ prec) {
    const int b = blockIdx.x;          // q0 = b, q1 = b + 256
    const int t = threadIdx.x;         // 0..511 (8 waves)
    const int lane = t & 63, wave = t >> 6;
    const int q0 = b, q1 = b + 256;

    __shared__ float s0[N];            // C-scaled distance row of q0
    __shared__ float s1[N];            // C-scaled distance row of q1
    __shared__ float4 eq0[NF4];        // emb[q0]
    __shared__ float4 eq1[NF4];        // emb[q1]
    __shared__ short gt0[N], gt1[N];   // GT column indices
    __shared__ int n0, n1;
    __shared__ float wnum[8];

    if (t == 0) { n0 = 0; n1 = 0; }
    const float4* embf4 = (const float4*)emb;
    if (t < NF4)            eq0[t]        = embf4[(size_t)q0 * NF4 + t];
    else if (t < 2 * NF4)   eq1[t - NF4]  = embf4[(size_t)q1 * NF4 + (t - NF4)];
    __syncthreads();

    // ---- Phase 1: distances (diff^2 form, k-sequential accumulation order
    //      matches the previously-verified kernel's numerics) ----
    float a0 = 0.f, a1 = 0.f;
    const float4* rowp = embf4 + (size_t)t * NF4;
#pragma unroll 8
    for (int k = 0; k < NF4; ++k) {
        float4 v  = rowp[k];
        float4 u0 = eq0[k];            // broadcast LDS read (conflict-free)
        float4 u1 = eq1[k];
        float e;
        e = v.x - u0.x; a0 += e * e;  e = v.y - u0.y; a0 += e * e;
        e = v.z - u0.z; a0 += e * e;  e = v.w - u0.w; a0 += e * e;
        e = v.x - u1.x; a1 += e * e;  e = v.y - u1.y; a1 += e * e;
        e = v.z - u1.z; a1 += e * e;  e = v.w - u1.w; a1 += e * e;
    }
    const float C = 144.26950408889634f;  // (1/T2) * log2(e)
    float d0 = sqrtf(fmaxf(a0, 1e-12f)) * C;
    float d1 = sqrtf(fmaxf(a1, 1e-12f)) * C;
    if (t == q0) d0 = 1e6f * C;        // self pair -> BIG (exp2 overflow -> term 0)
    if (t == q1) d1 = 1e6f * C;
    s0[t] = d0;
    s1[t] = d1;

    const int lt  = labels[t];
    const int lq0 = labels[q0], lq1 = labels[q1];
    if (lt == lq0 && t != q0) { int p = atomicAdd(&n0, 1); gt0[p] = (short)t; }
    if (lt == lq1 && t != q1) { int p = atomicAdd(&n1, 1); gt1[p] = (short)t; }
    __syncthreads();

    // ---- Phase 2: soft-rank only for GT columns ----
    const float* s  = (wave < 4) ? s0 : s1;
    const short* gt = (wave < 4) ? gt0 : gt1;
    const int    n  = (wave < 4) ? n0 : n1;
    const int    wq = wave & 3;
    float mynum = 0.f;
    for (int i = wq; i < n; i += 4) {
        const float sj = s[gt[i]];
        float r = 0.f;
#pragma unroll
        for (int m = lane; m < N; m += 64)       // 8 iters, stride-1 LDS
            r += RCPF(1.f + EXP2F(s[m] - sj));   // sigmoid((d_j - d_m)/T2)
#pragma unroll
        for (int off = 32; off > 0; off >>= 1) r += __shfl_down(r, off);
        if (lane == 0)
            mynum += RCPF(1.f + EXP2F((r - 5.f) * 1.4426950408889634f));
    }
    if (lane == 0) wnum[wave] = mynum;
    __syncthreads();
    if (t == 0) {
        float num0 = wnum[0] + wnum[1] + wnum[2] + wnum[3];
        prec[q0] = num0 / fminf((float)n0, 5.f);   // n==0 -> NaN, matches ref
    } else if (t == 64) {
        float num1 = wnum[4] + wnum[5] + wnum[6] + wnum[7];
        prec[q1] = num1 / fminf((float)n1, 5.f);
    }
}

// out = 1 - mean(prec)
__global__ __launch_bounds__(256) void final_kernel(const float* __restrict__ prec,
                                                    float* __restrict__ out) {
    const int t = threadIdx.x;
    const int lane = t & 63, wave = t >> 6;
    __shared__ float w[4];
    float v = prec[t] + prec[t + 256];
#pragma unroll
    for (int off = 32; off > 0; off >>= 1) v += __shfl_down(v, off);
    if (lane == 0) w[wave] = v;
    __syncthreads();
    if (t == 0) out[0] = 1.0f - (w[0] + w[1] + w[2] + w[3]) * (1.0f / 512.0f);
}

extern "C" void kernel_launch(void* const* d_in, const int* in_sizes, int n_in,
                              void* d_out, int out_size, void* d_ws, size_t ws_size,
                              hipStream_t stream) {
    const float* emb  = (const float*)d_in[0];
    const int* labels = (const int*)d_in[1];
    float* out        = (float*)d_out;
    float* prec       = (float*)d_ws;    // 512 floats

    hipLaunchKernelGGL(fused_kernel, dim3(N / 2), dim3(512), 0, stream,
                       emb, labels, prec);
    hipLaunchKernelGGL(final_kernel, dim3(1), dim3(256), 0, stream, prec, out);
}

// Round 2
// 71.230 us; speedup vs baseline: 1.2440x; 1.2440x over previous
//
#include <hip/hip_runtime.h>

#define N 512
#define D 384
#define NF4 (D / 4)   // 96 float4 per embedding row

#if __has_builtin(__builtin_amdgcn_exp2f)
#define EXP2F(x) __builtin_amdgcn_exp2f(x)
#else
#define EXP2F(x) exp2f(x)
#endif
#if __has_builtin(__builtin_amdgcn_rcpf)
#define RCPF(x) __builtin_amdgcn_rcpf(x)
#else
#define RCPF(x) (1.0f / (x))
#endif

// Fused dist+loss: one block per query pair {b, b+256}, 512 threads.
//
// Phase 1 (coalesced, the round-1 fix): each 16-lane group owns one gallery
// row j; lane p reads float4 k4 = p + 16*i (6 iters) -> 16 lanes cover 256
// contiguous bytes, a wave touches 4 rows = 16 cache lines per instruction
// (vs 64 for the round-1 per-lane-row pattern). emb (786 KB) is L2-resident;
// aggregate traffic 256 blocks x 786 KB = 201 MB ~= 5.8 us at L2 BW.
// Partial d^2 reduces across the 16-lane group via __shfl_down(.,off,16).
//
// Phase 2: identical to the verified round-1 code. Distance rows (pre-scaled
// by C = (1/T2)*log2(e)) never touch global memory.
__global__ __launch_bounds__(512) void fused_kernel(const float* __restrict__ emb,
                                                    const int* __restrict__ labels,
                                                    float* __restrict__ prec) {
    const int b = blockIdx.x;          // q0 = b, q1 = b + 256
    const int t = threadIdx.x;         // 0..511 (8 waves)
    const int lane = t & 63, wave = t >> 6;
    const int g = lane >> 4, p = lane & 15;   // 16-lane group, pos in group
    const int q0 = b, q1 = b + 256;

    __shared__ float s0[N];            // C-scaled distance row of q0
    __shared__ float s1[N];            // C-scaled distance row of q1
    __shared__ float4 eq0[NF4];        // emb[q0]
    __shared__ float4 eq1[NF4];        // emb[q1]
    __shared__ short gt0[N], gt1[N];   // GT column indices
    __shared__ int n0, n1;
    __shared__ float wnum[8];

    if (t == 0) { n0 = 0; n1 = 0; }
    const float4* embf4 = (const float4*)emb;
    if (t < NF4)            eq0[t]       = embf4[(size_t)q0 * NF4 + t];
    else if (t < 2 * NF4)   eq1[t - NF4] = embf4[(size_t)q1 * NF4 + (t - NF4)];
    __syncthreads();

    const float C = 144.26950408889634f;  // (1/T2) * log2(e)
    const int rowId = wave * 4 + g;       // 0..31: row offset within a pass

#pragma unroll 2
    for (int pass = 0; pass < 16; ++pass) {
        const int j = pass * 32 + rowId;
        const float4* rp = embf4 + (size_t)j * NF4;
        float a0 = 0.f, a1 = 0.f;
#pragma unroll
        for (int i = 0; i < 6; ++i) {
            const int k4 = p + 16 * i;
            float4 v  = rp[k4];           // 16 lanes: 256 B contiguous
            float4 u0 = eq0[k4];          // b128, 2-way bank alias (free)
            float4 u1 = eq1[k4];
            float e;
            e = v.x - u0.x; a0 += e * e;  e = v.y - u0.y; a0 += e * e;
            e = v.z - u0.z; a0 += e * e;  e = v.w - u0.w; a0 += e * e;
            e = v.x - u1.x; a1 += e * e;  e = v.y - u1.y; a1 += e * e;
            e = v.z - u1.z; a1 += e * e;  e = v.w - u1.w; a1 += e * e;
        }
#pragma unroll
        for (int off = 8; off > 0; off >>= 1) {
            a0 += __shfl_down(a0, off, 16);
            a1 += __shfl_down(a1, off, 16);
        }
        if (p == 0) {
            float d0 = sqrtf(fmaxf(a0, 1e-12f)) * C;
            float d1 = sqrtf(fmaxf(a1, 1e-12f)) * C;
            if (j == q0) d0 = 1e6f * C;   // self pair -> BIG
            if (j == q1) d1 = 1e6f * C;
            s0[j] = d0;
            s1[j] = d1;
        }
    }

    const int lt  = labels[t];
    const int lq0 = labels[q0], lq1 = labels[q1];
    if (lt == lq0 && t != q0) { int pi = atomicAdd(&n0, 1); gt0[pi] = (short)t; }
    if (lt == lq1 && t != q1) { int pi = atomicAdd(&n1, 1); gt1[pi] = (short)t; }
    __syncthreads();

    // ---- Phase 2: soft-rank only for GT columns (~8 of 512 per query) ----
    const float* s  = (wave < 4) ? s0 : s1;
    const short* gt = (wave < 4) ? gt0 : gt1;
    const int    n  = (wave < 4) ? n0 : n1;
    const int    wq = wave & 3;
    float mynum = 0.f;
    for (int i = wq; i < n; i += 4) {
        const float sj = s[gt[i]];
        float r = 0.f;
#pragma unroll
        for (int m = lane; m < N; m += 64)       // 8 iters, stride-1 LDS
            r += RCPF(1.f + EXP2F(s[m] - sj));   // sigmoid((d_j - d_m)/T2)
#pragma unroll
        for (int off = 32; off > 0; off >>= 1) r += __shfl_down(r, off);
        if (lane == 0)
            mynum += RCPF(1.f + EXP2F((r - 5.f) * 1.4426950408889634f));
    }
    if (lane == 0) wnum[wave] = mynum;
    __syncthreads();
    if (t == 0) {
        float num0 = wnum[0] + wnum[1] + wnum[2] + wnum[3];
        prec[q0] = num0 / fminf((float)n0, 5.f);   // n==0 -> NaN, matches ref
    } else if (t == 64) {
        float num1 = wnum[4] + wnum[5] + wnum[6] + wnum[7];
        prec[q1] = num1 / fminf((float)n1, 5.f);
    }
}

// out = 1 - mean(prec)
__global__ __launch_bounds__(256) void final_kernel(const float* __restrict__ prec,
                                                    float* __restrict__ out) {
    const int t = threadIdx.x;
    const int lane = t & 63, wave = t >> 6;
    __shared__ float w[4];
    float v = prec[t] + prec[t + 256];
#pragma unroll
    for (int off = 32; off > 0; off >>= 1) v += __shfl_down(v, off);
    if (lane == 0) w[wave] = v;
    __syncthreads();
    if (t == 0) out[0] = 1.0f - (w[0] + w[1] + w[2] + w[3]) * (1.0f / 512.0f);
}

extern "C" void kernel_launch(void* const* d_in, const int* in_sizes, int n_in,
                              void* d_out, int out_size, void* d_ws, size_t ws_size,
                              hipStream_t stream) {
    const float* emb  = (const float*)d_in[0];
    const int* labels = (const int*)d_in[1];
    float* out        = (float*)d_out;
    float* prec       = (float*)d_ws;    // 512 floats

    hipLaunchKernelGGL(fused_kernel, dim3(N / 2), dim3(512), 0, stream,
                       emb, labels, prec);
    hipLaunchKernelGGL(final_kernel, dim3(1), dim3(256), 0, stream, prec, out);
}

// Round 3
// 70.047 us; speedup vs baseline: 1.2650x; 1.0169x over previous
//
#include <hip/hip_runtime.h>

#define N 512
#define D 384
#define NF4 (D / 4)   // 96 float4 per embedding row

#if __has_builtin(__builtin_amdgcn_exp2f)
#define EXP2F(x) __builtin_amdgcn_exp2f(x)
#else
#define EXP2F(x) exp2f(x)
#endif
#if __has_builtin(__builtin_amdgcn_rcpf)
#define RCPF(x) __builtin_amdgcn_rcpf(x)
#else
#define RCPF(x) (1.0f / (x))
#endif

// 16-lane-row inclusive suffix-sum via DPP (VALU pipe, not LDS pipe).
// row_shr:N = dest lane i reads src lane i-N (data moves toward higher
// lanes); bound_ctrl=true zero-fills lanes i<N. After shr 1,2,4,8 the
// full 16-lane sum sits in lane 15 of each row (classic GCN reduction).
__device__ __forceinline__ float row16_sum(float x) {
    int v;
    v = __builtin_amdgcn_update_dpp(0, __float_as_int(x), 0x111, 0xF, 0xF, true);
    x += __int_as_float(v);
    v = __builtin_amdgcn_update_dpp(0, __float_as_int(x), 0x112, 0xF, 0xF, true);
    x += __int_as_float(v);
    v = __builtin_amdgcn_update_dpp(0, __float_as_int(x), 0x114, 0xF, 0xF, true);
    x += __int_as_float(v);
    v = __builtin_amdgcn_update_dpp(0, __float_as_int(x), 0x118, 0xF, 0xF, true);
    x += __int_as_float(v);
    return x;
}

// Fused dist+loss: one block per query pair {b, b+256}, 512 threads.
// Phase 1 (round-3 fix): query fragments live in REGISTERS (lane p only
// needs eq[p+16i], 6 float4 per query = 48 VGPR for both) and the 16-lane
// reduce uses DPP. The hot loop's LDS-pipe traffic (12 ds_read_b128 +
// 8 ds_bpermute per wave-pass = ~11 us/CU serialized in round 2) drops to
// 2 ds_write_b32 per group-pass. Global reads stay coalesced: 16 lanes
// cover 256 contiguous bytes of row j; emb is L2-resident (786 KB/XCD).
// Phase 2: byte-identical to the verified round-2 code.
__global__ __launch_bounds__(512) void fused_kernel(const float* __restrict__ emb,
                                                    const int* __restrict__ labels,
                                                    float* __restrict__ prec) {
    const int b = blockIdx.x;          // q0 = b, q1 = b + 256
    const int t = threadIdx.x;         // 0..511 (8 waves)
    const int lane = t & 63, wave = t >> 6;
    const int g = lane >> 4, p = lane & 15;   // 16-lane group, pos in group
    const int q0 = b, q1 = b + 256;

    __shared__ float s0[N];            // C-scaled distance row of q0
    __shared__ float s1[N];            // C-scaled distance row of q1
    __shared__ short gt0[N], gt1[N];   // GT column indices
    __shared__ int n0, n1;
    __shared__ float wnum[8];

    if (t == 0) { n0 = 0; n1 = 0; }
    __syncthreads();                   // order n0/n1 init before atomics

    // Build GT lists (overlaps with phase-1 issue; no barrier needed until
    // phase 2 -- the phase-1/phase-2 barrier covers both s[] and gt[]).
    const int lt  = labels[t];
    const int lq0 = labels[q0], lq1 = labels[q1];
    if (lt == lq0 && t != q0) { int pi = atomicAdd(&n0, 1); gt0[pi] = (short)t; }
    if (lt == lq1 && t != q1) { int pi = atomicAdd(&n1, 1); gt1[pi] = (short)t; }

    // Query fragments -> registers (L2-served broadcast, one-time).
    const float4* embf4 = (const float4*)emb;
    float4 u0[6], u1[6];
#pragma unroll
    for (int i = 0; i < 6; ++i) {
        u0[i] = embf4[(size_t)q0 * NF4 + p + 16 * i];
        u1[i] = embf4[(size_t)q1 * NF4 + p + 16 * i];
    }

    const float C = 144.26950408889634f;  // (1/T2) * log2(e)
    const int rowId = (wave << 2) + g;    // 0..31: row offset within a pass

#pragma unroll 2
    for (int pass = 0; pass < 16; ++pass) {
        const int j = (pass << 5) + rowId;
        const float4* rp = embf4 + (size_t)j * NF4 + p;
        float a0 = 0.f, a1 = 0.f;
#pragma unroll
        for (int i = 0; i < 6; ++i) {
            float4 v = rp[16 * i];        // 16 lanes: 256 B contiguous
            float e;
            e = v.x - u0[i].x; a0 += e * e;  e = v.y - u0[i].y; a0 += e * e;
            e = v.z - u0[i].z; a0 += e * e;  e = v.w - u0[i].w; a0 += e * e;
            e = v.x - u1[i].x; a1 += e * e;  e = v.y - u1[i].y; a1 += e * e;
            e = v.z - u1[i].z; a1 += e * e;  e = v.w - u1[i].w; a1 += e * e;
        }
        a0 = row16_sum(a0);               // sum -> lane p==15 of each group
        a1 = row16_sum(a1);
        if (p == 15) {
            float d0 = sqrtf(fmaxf(a0, 1e-12f)) * C;
            float d1 = sqrtf(fmaxf(a1, 1e-12f)) * C;
            if (j == q0) d0 = 1e6f * C;   // self pair -> BIG
            if (j == q1) d1 = 1e6f * C;
            s0[j] = d0;
            s1[j] = d1;
        }
    }
    __syncthreads();

    // ---- Phase 2: soft-rank only for GT columns (~8 of 512 per query) ----
    const float* s  = (wave < 4) ? s0 : s1;
    const short* gt = (wave < 4) ? gt0 : gt1;
    const int    n  = (wave < 4) ? n0 : n1;
    const int    wq = wave & 3;
    float mynum = 0.f;
    for (int i = wq; i < n; i += 4) {
        const float sj = s[gt[i]];
        float r = 0.f;
#pragma unroll
        for (int m = lane; m < N; m += 64)       // 8 iters, stride-1 LDS
            r += RCPF(1.f + EXP2F(s[m] - sj));   // sigmoid((d_j - d_m)/T2)
#pragma unroll
        for (int off = 32; off > 0; off >>= 1) r += __shfl_down(r, off);
        if (lane == 0)
            mynum += RCPF(1.f + EXP2F((r - 5.f) * 1.4426950408889634f));
    }
    if (lane == 0) wnum[wave] = mynum;
    __syncthreads();
    if (t == 0) {
        float num0 = wnum[0] + wnum[1] + wnum[2] + wnum[3];
        prec[q0] = num0 / fminf((float)n0, 5.f);   // n==0 -> NaN, matches ref
    } else if (t == 64) {
        float num1 = wnum[4] + wnum[5] + wnum[6] + wnum[7];
        prec[q1] = num1 / fminf((float)n1, 5.f);
    }
}

// out = 1 - mean(prec)
__global__ __launch_bounds__(256) void final_kernel(const float* __restrict__ prec,
                                                    float* __restrict__ out) {
    const int t = threadIdx.x;
    const int lane = t & 63, wave = t >> 6;
    __shared__ float w[4];
    float v = prec[t] + prec[t + 256];
#pragma unroll
    for (int off = 32; off > 0; off >>= 1) v += __shfl_down(v, off);
    if (lane == 0) w[wave] = v;
    __syncthreads();
    if (t == 0) out[0] = 1.0f - (w[0] + w[1] + w[2] + w[3]) * (1.0f / 512.0f);
}

extern "C" void kernel_launch(void* const* d_in, const int* in_sizes, int n_in,
                              void* d_out, int out_size, void* d_ws, size_t ws_size,
                              hipStream_t stream) {
    const float* emb  = (const float*)d_in[0];
    const int* labels = (const int*)d_in[1];
    float* out        = (float*)d_out;
    float* prec       = (float*)d_ws;    // 512 floats

    hipLaunchKernelGGL(fused_kernel, dim3(N / 2), dim3(512), 0, stream,
                       emb, labels, prec);
    hipLaunchKernelGGL(final_kernel, dim3(1), dim3(256), 0, stream, prec, out);
}